// Round 1
// baseline (49.687 us; speedup 1.0000x reference)
//
#include <hip/hip_runtime.h>

#define BB 4
#define SS 4096
#define HH 2048
#define KK 2048   // int(0.5 * 4096)

// One wave (64 lanes) per row. Each lane: 8 x float4 = 32 elements.
// fp64 accumulation so score ordering matches the numpy fp32 reference
// far below the expected order-statistic gap.
__global__ void scores_kernel(const float* __restrict__ hs,
                              const float* __restrict__ gw,
                              float* __restrict__ scores) {
    int row  = blockIdx.x * 4 + (threadIdx.x >> 6);
    int lane = threadIdx.x & 63;
    const float4* x4 = reinterpret_cast<const float4*>(hs + (size_t)row * HH);
    const float4* g4 = reinterpret_cast<const float4*>(gw);
    double acc = 0.0;
#pragma unroll
    for (int i = 0; i < 8; ++i) {
        float4 a = x4[i * 64 + lane];
        float4 g = g4[i * 64 + lane];
        acc = fma((double)a.x, (double)g.x, acc);
        acc = fma((double)a.y, (double)g.y, acc);
        acc = fma((double)a.z, (double)g.z, acc);
        acc = fma((double)a.w, (double)g.w, acc);
    }
#pragma unroll
    for (int off = 32; off >= 1; off >>= 1)
        acc += __shfl_down(acc, off);
    if (lane == 0) scores[row] = (float)acc;
}

// One block per batch. 44-bit key = (orderable fp32 << 12) | (4095 - s):
// unique keys, tie-break = lower index wins (matches jax.lax.top_k).
// MSB-first binary search for the k-th largest key via block-wide counts.
__global__ void __launch_bounds__(1024)
topk_mask_kernel(const float* __restrict__ scores, float* __restrict__ mask) {
    int b   = blockIdx.x;
    int tid = threadIdx.x;
    const float* sc = scores + b * SS;

    unsigned long long key[4];
#pragma unroll
    for (int i = 0; i < 4; ++i) {
        int s = tid + i * 1024;
        unsigned u   = __float_as_uint(sc[s]);
        unsigned ord = (u & 0x80000000u) ? ~u : (u | 0x80000000u);
        key[i] = (((unsigned long long)ord) << 12) | (unsigned long long)(4095 - s);
    }

    __shared__ int wcnt[16];
    __shared__ int flag;
    unsigned long long cur = 0ULL;

    for (int bit = 43; bit >= 0; --bit) {
        unsigned long long cand = cur | (1ULL << bit);
        int c = 0;
#pragma unroll
        for (int i = 0; i < 4; ++i) c += (key[i] >= cand) ? 1 : 0;
#pragma unroll
        for (int off = 32; off >= 1; off >>= 1) c += __shfl_down(c, off);
        if ((tid & 63) == 0) wcnt[tid >> 6] = c;
        __syncthreads();
        if (tid == 0) {
            int tot = 0;
#pragma unroll
            for (int w = 0; w < 16; ++w) tot += wcnt[w];
            flag = (tot >= KK) ? 1 : 0;
        }
        __syncthreads();
        if (flag) cur = cand;
    }

#pragma unroll
    for (int i = 0; i < 4; ++i) {
        int s = tid + i * 1024;
        mask[b * SS + s] = (key[i] >= cur) ? 1.0f : 0.0f;
    }
}

extern "C" void kernel_launch(void* const* d_in, const int* in_sizes, int n_in,
                              void* d_out, int out_size, void* d_ws, size_t ws_size,
                              hipStream_t stream) {
    const float* hs = (const float*)d_in[0];   // [B, S, H] fp32
    const float* gw = (const float*)d_in[1];   // [1, H] fp32
    float* out    = (float*)d_out;
    float* mask   = out;            // first output chunk  [B*S]
    float* scores = out + BB * SS;  // second output chunk [B*S]

    scores_kernel<<<BB * SS / 4, 256, 0, stream>>>(hs, gw, scores);
    topk_mask_kernel<<<BB, 1024, 0, stream>>>(scores, mask);
}

// Round 2
// 39.528 us; speedup vs baseline: 1.2570x; 1.2570x over previous
//
#include <hip/hip_runtime.h>

#define BB 4
#define SS 4096
#define HH 2048
#define KK 2048   // int(0.5 * 4096)

// One wave (64 lanes) per row; 4 rows per 256-thread block.
// Each lane: 8 x float4 = 32 elements. fp64 accumulation (4 independent
// chains) so score ordering matches the fp32 reference far below the
// order-statistic gap; fp64 FLOP cost is ~1 us chip-wide (memory-bound).
__global__ void __launch_bounds__(256)
scores_kernel(const float* __restrict__ hs,
              const float* __restrict__ gw,
              float* __restrict__ scores) {
    int row  = blockIdx.x * 4 + (threadIdx.x >> 6);
    int lane = threadIdx.x & 63;
    const float4* x4 = reinterpret_cast<const float4*>(hs + (size_t)row * HH);
    const float4* g4 = reinterpret_cast<const float4*>(gw);

    float4 a[8], g[8];
#pragma unroll
    for (int i = 0; i < 8; ++i) a[i] = x4[i * 64 + lane];
#pragma unroll
    for (int i = 0; i < 8; ++i) g[i] = g4[i * 64 + lane];

    double ax = 0.0, ay = 0.0, az = 0.0, aw = 0.0;
#pragma unroll
    for (int i = 0; i < 8; ++i) {
        ax = fma((double)a[i].x, (double)g[i].x, ax);
        ay = fma((double)a[i].y, (double)g[i].y, ay);
        az = fma((double)a[i].z, (double)g[i].z, az);
        aw = fma((double)a[i].w, (double)g[i].w, aw);
    }
    double acc = (ax + ay) + (az + aw);
#pragma unroll
    for (int off = 32; off >= 1; off >>= 1)
        acc += __shfl_down(acc, off);
    if (lane == 0) scores[row] = (float)acc;
}

// One WAVE per batch (4 blocks x 64 threads), zero barriers.
// 64 orderable-uint keys per lane held in registers. MSB-first binary
// search for the largest T with count(ord >= T) >= K, with early exit
// when count == K exactly (threshold ~0.0 for N(0,1) scores => huge
// bit-space gap => exits in a few rounds). Ties at T broken by lowest
// global index via ballot-prefix ranking (matches jax.lax.top_k).
__global__ void __launch_bounds__(64)
topk_mask_kernel(const float* __restrict__ scores, float* __restrict__ mask) {
    int b    = blockIdx.x;
    int lane = threadIdx.x;
    const float* sc = scores + b * SS;

    unsigned ord[64];
#pragma unroll
    for (int i = 0; i < 64; ++i) {
        unsigned u = __float_as_uint(sc[i * 64 + lane]);
        ord[i] = (u & 0x80000000u) ? ~u : (u | 0x80000000u);
    }

    unsigned cur = 0u;
    for (int bit = 31; bit >= 0; --bit) {
        unsigned cand = cur | (1u << bit);
        int c = 0;
#pragma unroll
        for (int i = 0; i < 64; ++i) c += (ord[i] >= cand) ? 1 : 0;
#pragma unroll
        for (int off = 32; off >= 1; off >>= 1) c += __shfl_down(c, off);
        c = __shfl(c, 0);
        if (c >= KK) cur = cand;
        if (c == KK) break;   // cand separates exactly top-K
    }

    // strictly-greater count -> number of ties to admit (lowest index first)
    int cg = 0;
#pragma unroll
    for (int i = 0; i < 64; ++i) cg += (ord[i] > cur) ? 1 : 0;
#pragma unroll
    for (int off = 32; off >= 1; off >>= 1) cg += __shfl_down(cg, off);
    cg = __shfl(cg, 0);
    int r = KK - cg;

    unsigned long long lane_lt = (lane == 0) ? 0ull : (~0ull >> (64 - lane));
    int tiepfx = 0;
    float* mrow = mask + b * SS;
#pragma unroll
    for (int i = 0; i < 64; ++i) {
        bool gt  = ord[i] > cur;
        bool tie = ord[i] == cur;
        unsigned long long bal = __ballot(tie);
        int rank = tiepfx + __popcll(bal & lane_lt);
        mrow[i * 64 + lane] = (gt || (tie && rank < r)) ? 1.0f : 0.0f;
        tiepfx += __popcll(bal);
    }
}

extern "C" void kernel_launch(void* const* d_in, const int* in_sizes, int n_in,
                              void* d_out, int out_size, void* d_ws, size_t ws_size,
                              hipStream_t stream) {
    const float* hs = (const float*)d_in[0];   // [B, S, H] fp32
    const float* gw = (const float*)d_in[1];   // [1, H] fp32
    float* out    = (float*)d_out;
    float* mask   = out;            // first output chunk  [B*S]
    float* scores = out + BB * SS;  // second output chunk [B*S]

    scores_kernel<<<BB * SS / 4, 256, 0, stream>>>(hs, gw, scores);
    topk_mask_kernel<<<BB, 64, 0, stream>>>(scores, mask);
}

// Round 4
// 39.257 us; speedup vs baseline: 1.2657x; 1.0069x over previous
//
#include <hip/hip_runtime.h>

#define BB 4
#define SS 4096
#define HH 2048
#define KK 2048   // int(0.5 * 4096)

typedef float f4 __attribute__((ext_vector_type(4)));   // native vec for nontemporal builtin

// ---- scores: one wave per 4 consecutive rows, gate cached in registers ----

__device__ __forceinline__ void load_row(const f4* __restrict__ base, int lane,
                                         f4 (&buf)[8]) {
#pragma unroll
    for (int i = 0; i < 8; ++i)
        buf[i] = __builtin_nontemporal_load(&base[i * 64 + lane]);
}

__device__ __forceinline__ double dot_row(const f4 (&a)[8], const f4 (&g)[8]) {
    double ax = 0.0, ay = 0.0, az = 0.0, aw = 0.0;
#pragma unroll
    for (int i = 0; i < 8; ++i) {
        ax = fma((double)a[i].x, (double)g[i].x, ax);
        ay = fma((double)a[i].y, (double)g[i].y, ay);
        az = fma((double)a[i].z, (double)g[i].z, az);
        aw = fma((double)a[i].w, (double)g[i].w, aw);
    }
    return (ax + ay) + (az + aw);
}

__device__ __forceinline__ void reduce_store(double acc, int lane, float* __restrict__ dst) {
#pragma unroll
    for (int off = 32; off >= 1; off >>= 1)
        acc += __shfl_down(acc, off);
    if (lane == 0) *dst = (float)acc;
}

// 256 threads = 4 waves; each wave owns 4 consecutive rows -> 16 rows/block.
// Gate (8 KB) loaded once per wave into registers; hs rows ping-pong through
// A/B register buffers so the next row's loads are in flight during compute.
__global__ void __launch_bounds__(256)
scores_kernel(const float* __restrict__ hs,
              const float* __restrict__ gw,
              float* __restrict__ scores) {
    int wave = threadIdx.x >> 6;
    int lane = threadIdx.x & 63;
    int row0 = blockIdx.x * 16 + wave * 4;

    const f4* g4 = reinterpret_cast<const f4*>(gw);
    f4 g[8];
#pragma unroll
    for (int i = 0; i < 8; ++i) g[i] = g4[i * 64 + lane];

    const f4* r0 = reinterpret_cast<const f4*>(hs + (size_t)row0 * HH);
    // consecutive rows are 512 float4 apart
    f4 A[8], B[8];
    load_row(r0 + 0 * 512, lane, A);
    load_row(r0 + 1 * 512, lane, B);
    double d0 = dot_row(A, g);
    load_row(r0 + 2 * 512, lane, A);
    double d1 = dot_row(B, g);
    load_row(r0 + 3 * 512, lane, B);
    double d2 = dot_row(A, g);
    double d3 = dot_row(B, g);

    reduce_store(d0, lane, scores + row0 + 0);
    reduce_store(d1, lane, scores + row0 + 1);
    reduce_store(d2, lane, scores + row0 + 2);
    reduce_store(d3, lane, scores + row0 + 3);
}

// ---- topk: one wave per batch, register-resident keys, exact selection ----
__global__ void __launch_bounds__(64)
topk_mask_kernel(const float* __restrict__ scores, float* __restrict__ mask) {
    int b    = blockIdx.x;
    int lane = threadIdx.x;
    const float* sc = scores + b * SS;

    unsigned ord[64];
#pragma unroll
    for (int i = 0; i < 64; ++i) {
        unsigned u = __float_as_uint(sc[i * 64 + lane]);
        ord[i] = (u & 0x80000000u) ? ~u : (u | 0x80000000u);
    }

    unsigned cur = 0u;
    for (int bit = 31; bit >= 0; --bit) {
        unsigned cand = cur | (1u << bit);
        int c = 0;
#pragma unroll
        for (int i = 0; i < 64; ++i) c += (ord[i] >= cand) ? 1 : 0;
#pragma unroll
        for (int off = 32; off >= 1; off >>= 1) c += __shfl_down(c, off);
        c = __shfl(c, 0);
        if (c >= KK) cur = cand;
        if (c == KK) break;   // cand separates exactly top-K
    }

    int cg = 0;
#pragma unroll
    for (int i = 0; i < 64; ++i) cg += (ord[i] > cur) ? 1 : 0;
#pragma unroll
    for (int off = 32; off >= 1; off >>= 1) cg += __shfl_down(cg, off);
    cg = __shfl(cg, 0);
    int r = KK - cg;   // ties to admit, lowest index first

    unsigned long long lane_lt = (lane == 0) ? 0ull : (~0ull >> (64 - lane));
    int tiepfx = 0;
    float* mrow = mask + b * SS;
#pragma unroll
    for (int i = 0; i < 64; ++i) {
        bool gt  = ord[i] > cur;
        bool tie = ord[i] == cur;
        unsigned long long bal = __ballot(tie);
        int rank = tiepfx + __popcll(bal & lane_lt);
        mrow[i * 64 + lane] = (gt || (tie && rank < r)) ? 1.0f : 0.0f;
        tiepfx += __popcll(bal);
    }
}

extern "C" void kernel_launch(void* const* d_in, const int* in_sizes, int n_in,
                              void* d_out, int out_size, void* d_ws, size_t ws_size,
                              hipStream_t stream) {
    const float* hs = (const float*)d_in[0];   // [B, S, H] fp32
    const float* gw = (const float*)d_in[1];   // [1, H] fp32
    float* out    = (float*)d_out;
    float* mask   = out;            // first output chunk  [B*S]
    float* scores = out + BB * SS;  // second output chunk [B*S]

    scores_kernel<<<BB * SS / 16, 256, 0, stream>>>(hs, gw, scores);
    topk_mask_kernel<<<BB, 64, 0, stream>>>(scores, mask);
}